// Round 5
// baseline (318.815 us; speedup 1.0000x reference)
//
#include <hip/hip_runtime.h>

// ContentBasedAttention: y = softmax(cos_sim(x1@WQ, x2@WK)) @ (x2@WV)
// B=4, S=2048, D=1024. fp32 in/out; internal bf16 MFMA.
// GEMM engine (m201-style): BK=64, 2 LDS buffers, 4 phases/K-tile, each phase
// computes one C-quadrant (16 MFMA / 8 TALL) between raw barriers; both B-halves
// register-held (p3 has zero LDS reads); all prefetch loads for tile kt+1 issued
// at p0 of kt; single vmcnt(0) at p3-end (3-phase lead, ~zero wait). Paired-row
// XOR-swizzled LDS (round-3-proven conflict-free) via pre-swizzled gl_lds source.

typedef __attribute__((ext_vector_type(4))) float f32x4;
typedef __attribute__((ext_vector_type(4))) unsigned short u16x4;
typedef __attribute__((ext_vector_type(8))) unsigned short u16x8;
typedef __attribute__((ext_vector_type(8))) __bf16 bf16x8;

__device__ __forceinline__ unsigned short f2b(float f) {
  unsigned u = __float_as_uint(f);
  u += 0x7FFFu + ((u >> 16) & 1u);
  return (unsigned short)(u >> 16);
}
__device__ __forceinline__ float b2f(unsigned short h) {
  return __uint_as_float(((unsigned)h) << 16);
}

__device__ __forceinline__ void gl_lds16(const void* g, void* l) {
  __builtin_amdgcn_global_load_lds(
      (const __attribute__((address_space(1))) void*)g,
      (__attribute__((address_space(3))) void*)l, 16, 0, 0);
}

// ---------------- elementwise converts ----------------

__global__ void cvt_f32_bf16(const float* __restrict__ in, unsigned short* __restrict__ out) {
  long long i = (long long)(blockIdx.x * 256 + threadIdx.x) * 8;
  f32x4 a = *(const f32x4*)(in + i);
  f32x4 b = *(const f32x4*)(in + i + 4);
  u16x8 o;
  o[0] = f2b(a[0]); o[1] = f2b(a[1]); o[2] = f2b(a[2]); o[3] = f2b(a[3]);
  o[4] = f2b(b[0]); o[5] = f2b(b[1]); o[6] = f2b(b[2]); o[7] = f2b(b[3]);
  *(u16x8*)(out + i) = o;
}

__global__ void cvt_w_T(const float* __restrict__ w0, const float* __restrict__ w1,
                        const float* __restrict__ w2,
                        unsigned short* __restrict__ o0, unsigned short* __restrict__ o1,
                        unsigned short* __restrict__ o2) {
  const float* src = blockIdx.z == 0 ? w0 : (blockIdx.z == 1 ? w1 : w2);
  unsigned short* dst = blockIdx.z == 0 ? o0 : (blockIdx.z == 1 ? o1 : o2);
  __shared__ float tile[32][33];
  const int t = threadIdx.x;
  const int r = t >> 3, c4 = (t & 7) << 2;
  f32x4 v = *(const f32x4*)(src + (long long)(blockIdx.y * 32 + r) * 1024 + blockIdx.x * 32 + c4);
  tile[r][c4 + 0] = v[0]; tile[r][c4 + 1] = v[1];
  tile[r][c4 + 2] = v[2]; tile[r][c4 + 3] = v[3];
  __syncthreads();
  u16x4 ov;
  ov[0] = f2b(tile[c4 + 0][r]); ov[1] = f2b(tile[c4 + 1][r]);
  ov[2] = f2b(tile[c4 + 2][r]); ov[3] = f2b(tile[c4 + 3][r]);
  *(u16x4*)(dst + (long long)(blockIdx.x * 32 + r) * 1024 + blockIdx.y * 32 + c4) = ov;
}

// ---------------- per-row rsqrt(sum sq) ----------------

__global__ void rownorm(const unsigned short* __restrict__ qb, const unsigned short* __restrict__ kb,
                        float* __restrict__ rq, float* __restrict__ rk) {
  const int row = blockIdx.x;
  const unsigned short* src;
  float* dst;
  if (row < 8192) { src = qb + (long long)row * 1024; dst = rq + row; }
  else            { src = kb + (long long)(row - 8192) * 1024; dst = rk + (row - 8192); }
  const int t = threadIdx.x;
  u16x4 v = *(const u16x4*)(src + t * 4);
  float s = 0.f;
#pragma unroll
  for (int i = 0; i < 4; ++i) { float f = b2f(v[i]); s += f * f; }
#pragma unroll
  for (int o = 32; o; o >>= 1) s += __shfl_xor(s, o);
  __shared__ float red[4];
  if ((t & 63) == 0) red[t >> 6] = s;
  __syncthreads();
  if (t == 0) {
    float tot = red[0] + red[1] + red[2] + red[3];
    *dst = rsqrtf(fmaxf(tot, 1e-12f));
  }
}

// ---------------- in-place row softmax over bf16 [*, 2048] ----------------

__global__ void softmax_rows(unsigned short* __restrict__ zb) {
  unsigned short* zr = zb + (long long)blockIdx.x * 2048;
  const int t = threadIdx.x;
  u16x8 v = *(const u16x8*)(zr + t * 8);
  float f[8];
#pragma unroll
  for (int i = 0; i < 8; ++i) f[i] = b2f(v[i]);
  float mx = f[0];
#pragma unroll
  for (int i = 1; i < 8; ++i) mx = fmaxf(mx, f[i]);
#pragma unroll
  for (int o = 32; o; o >>= 1) mx = fmaxf(mx, __shfl_xor(mx, o));
  __shared__ float red[4];
  if ((t & 63) == 0) red[t >> 6] = mx;
  __syncthreads();
  mx = fmaxf(fmaxf(red[0], red[1]), fmaxf(red[2], red[3]));
  float s = 0.f;
#pragma unroll
  for (int i = 0; i < 8; ++i) { f[i] = __expf(f[i] - mx); s += f[i]; }
  __syncthreads();
#pragma unroll
  for (int o = 32; o; o >>= 1) s += __shfl_xor(s, o);
  if ((t & 63) == 0) red[t >> 6] = s;
  __syncthreads();
  s = red[0] + red[1] + red[2] + red[3];
  float inv = 1.0f / s;
  u16x8 o8;
#pragma unroll
  for (int i = 0; i < 8; ++i) o8[i] = f2b(f[i] * inv);
  *(u16x8*)(zr + t * 8) = o8;
}

// ---------------- GEMM_BT engine ----------------
// C[m,n] = sum_k A[m,k]*B[n,k], row-major bf16. BM = TALL?128:256, BN=256, BK=64.
// 512 threads = 8 waves (2M x 4N); wave tile (BM/2) x 64.
// LDS: sA/sB[2 buf][2 ks][rows*32], paired-row swizzle (slot ^= R&7) — 0 conflicts
// (round-3 measured). Phases per K-tile (mh = p>>1, nh phase order 0,1,1,0):
//   p0: read A(mh0) 8/4 + B(nh0) 4; STAGE all of tile kt+1 (8/6 loads, opposite buf)
//   p1: read B(nh1) 4          p2: read A(mh1) 8/4          p3: no reads
// each phase: barrier; lgkm(0); setprio(1); MFMA quadrant; setprio(0); barrier.
// vmcnt(0) only at p3-end (loads issued 3 phases earlier -> ~zero wait).
// MODE 0: bf16 C. MODE 1: bf16 of acc*rowS[m]*colS[n]. MODE 2: fp32 C.

template <int MODE, int TALL>
__global__ __launch_bounds__(512, 2) void gemmp(
    const unsigned short* __restrict__ A,
    const unsigned short* __restrict__ B0_, const unsigned short* __restrict__ B1_, int bSplit,
    void* __restrict__ C, int K, int lda, int ldb, int ldc,
    long long strideA, long long strideB, long long strideC,
    const float* __restrict__ rowS, const float* __restrict__ colS, int scaleStride) {
  constexpr int BM = TALL ? 128 : 256;
  constexpr int MH = TALL ? 2 : 4;   // m-frags per quadrant
  constexpr int MF = MH * 2;         // m-frags per wave
  constexpr int AE = BM * 32;
  __shared__ __align__(128) unsigned short sA[2][2][AE];
  __shared__ __align__(128) unsigned short sB[2][2][256 * 32];

  // bijective XCD swizzle (nwg = 256, %8 == 0)
  const int gx = gridDim.x, gy = gridDim.y;
  int flat = blockIdx.x + gx * (blockIdx.y + gy * blockIdx.z);
  const int cpx = (gx * gy * gridDim.z) >> 3;
  flat = (flat & 7) * cpx + (flat >> 3);
  const int bx = flat % gx;
  const int rem = flat / gx;
  const int by = rem % gy;
  const int bz = rem / gy;

  const int bm0 = by * BM, bn0 = bx << 8;
  const unsigned short* Ab = A + (long long)bz * strideA;
  const unsigned short* Bb = ((bm0 < bSplit) ? B0_ : B1_) + (long long)bz * strideB;

  const int t = threadIdx.x, l = t & 63, w = t >> 6;
  const int wr = w >> 2, wc = w & 3;
  const int fr = l & 15, fq = l >> 4;
  const long long ldaL = lda, ldbL = ldb;

  // swizzled per-lane read offset within a [rows][32] region
  const int R0 = fr >> 1;
  const int lofs = R0 * 64 + ((((fr & 1) << 2) | fq) ^ R0) * 8;

  // per-thread staging source (involution of the read swizzle)
  const int aq = (t & 7) ^ ((t >> 3) & 7);
  const int g0 = ((t >> 3) << 1) + (aq >> 2);
  const int q8 = (aq & 3) << 3;
  const unsigned short* gA_t = Ab + (long long)(bm0 + g0) * ldaL + q8;
  const unsigned short* gB_t = Bb + (long long)(bn0 + g0) * ldbL + q8;

  // stage one full K-tile (A: BM x 64, B: 256 x 64) into buffer nb
  auto STAGE = [&](int kc, int nb) {
#pragma unroll
    for (int ks = 0; ks < 2; ++ks) {
      gl_lds16(gA_t + kc + ks * 32, &sA[nb][ks][t * 8]);
      if constexpr (!TALL)
        gl_lds16(gA_t + (long long)128 * ldaL + kc + ks * 32, &sA[nb][ks][4096 + t * 8]);
      gl_lds16(gB_t + kc + ks * 32, &sB[nb][ks][t * 8]);
      gl_lds16(gB_t + (long long)128 * ldbL + kc + ks * 32, &sB[nb][ks][4096 + t * 8]);
    }
  };

  f32x4 acc[MF][4] = {};
  const int NKT = K >> 6;
  const int wrow = wr * (TALL ? 64 : 128);
  const int bcol = wc * 64;

  STAGE(0, 0);
  asm volatile("s_waitcnt vmcnt(0)" ::: "memory");
  __builtin_amdgcn_s_barrier();

  for (int kt = 0; kt < NKT; ++kt) {
    const int cur = kt & 1;
    const bool st = (kt + 1 < NKT);
    const unsigned short* A0p = &sA[cur][0][0];
    const unsigned short* A1p = &sA[cur][1][0];
    const unsigned short* B0p = &sB[cur][0][0];
    const unsigned short* B1p = &sB[cur][1][0];
    bf16x8 af[MH][2], b0[2][2], b1[2][2];

    // ---- p0: quadrant (mh0, nh0)
#pragma unroll
    for (int m = 0; m < MH; ++m) {
      af[m][0] = *(const bf16x8*)(A0p + (wrow + m * 16) * 32 + lofs);
      af[m][1] = *(const bf16x8*)(A1p + (wrow + m * 16) * 32 + lofs);
    }
#pragma unroll
    for (int n = 0; n < 2; ++n) {
      b0[n][0] = *(const bf16x8*)(B0p + (bcol + n * 16) * 32 + lofs);
      b0[n][1] = *(const bf16x8*)(B1p + (bcol + n * 16) * 32 + lofs);
    }
    if (st) STAGE((kt + 1) << 6, cur ^ 1);
    __builtin_amdgcn_s_barrier();
    asm volatile("s_waitcnt lgkmcnt(0)" ::: "memory");
    __builtin_amdgcn_s_setprio(1);
#pragma unroll
    for (int m = 0; m < MH; ++m)
#pragma unroll
      for (int n = 0; n < 2; ++n)
#pragma unroll
        for (int ks = 0; ks < 2; ++ks)
          acc[m][n] = __builtin_amdgcn_mfma_f32_16x16x32_bf16(af[m][ks], b0[n][ks], acc[m][n], 0, 0, 0);
    __builtin_amdgcn_s_setprio(0);
    __builtin_amdgcn_s_barrier();

    // ---- p1: quadrant (mh0, nh1)
#pragma unroll
    for (int n = 0; n < 2; ++n) {
      b1[n][0] = *(const bf16x8*)(B0p + (bcol + 32 + n * 16) * 32 + lofs);
      b1[n][1] = *(const bf16x8*)(B1p + (bcol + 32 + n * 16) * 32 + lofs);
    }
    __builtin_amdgcn_s_barrier();
    asm volatile("s_waitcnt lgkmcnt(0)" ::: "memory");
    __builtin_amdgcn_s_setprio(1);
#pragma unroll
    for (int m = 0; m < MH; ++m)
#pragma unroll
      for (int n = 0; n < 2; ++n)
#pragma unroll
        for (int ks = 0; ks < 2; ++ks)
          acc[m][2 + n] = __builtin_amdgcn_mfma_f32_16x16x32_bf16(af[m][ks], b1[n][ks], acc[m][2 + n], 0, 0, 0);
    __builtin_amdgcn_s_setprio(0);
    __builtin_amdgcn_s_barrier();

    // ---- p2: quadrant (mh1, nh1)
#pragma unroll
    for (int m = 0; m < MH; ++m) {
      af[m][0] = *(const bf16x8*)(A0p + (wrow + MH * 16 + m * 16) * 32 + lofs);
      af[m][1] = *(const bf16x8*)(A1p + (wrow + MH * 16 + m * 16) * 32 + lofs);
    }
    __builtin_amdgcn_s_barrier();
    asm volatile("s_waitcnt lgkmcnt(0)" ::: "memory");
    __builtin_amdgcn_s_setprio(1);
#pragma unroll
    for (int m = 0; m < MH; ++m)
#pragma unroll
      for (int n = 0; n < 2; ++n)
#pragma unroll
        for (int ks = 0; ks < 2; ++ks)
          acc[MH + m][2 + n] = __builtin_amdgcn_mfma_f32_16x16x32_bf16(af[m][ks], b1[n][ks], acc[MH + m][2 + n], 0, 0, 0);
    __builtin_amdgcn_s_setprio(0);
    __builtin_amdgcn_s_barrier();

    // ---- p3: quadrant (mh1, nh0) — zero LDS reads (b0 register-held)
    __builtin_amdgcn_s_setprio(1);
#pragma unroll
    for (int m = 0; m < MH; ++m)
#pragma unroll
      for (int n = 0; n < 2; ++n)
#pragma unroll
        for (int ks = 0; ks < 2; ++ks)
          acc[MH + m][n] = __builtin_amdgcn_mfma_f32_16x16x32_bf16(af[m][ks], b0[n][ks], acc[MH + m][n], 0, 0, 0);
    __builtin_amdgcn_s_setprio(0);
    if (st) asm volatile("s_waitcnt vmcnt(0)" ::: "memory");
    __builtin_amdgcn_s_barrier();
  }

  // epilogue: acc[m][j] -> row bm0 + wrow + m*16 + fq*4 + jj, col bn0 + bcol + j*16 + fr
  const int rbase = bm0 + wrow + fq * 4;
  const int c0 = bn0 + bcol + fr;
  if constexpr (MODE == 0) {
    unsigned short* Cp = (unsigned short*)C + (long long)bz * strideC;
#pragma unroll
    for (int m = 0; m < MF; ++m)
#pragma unroll
      for (int jj = 0; jj < 4; ++jj) {
        const long long rb = (long long)(rbase + m * 16 + jj) * ldc + c0;
#pragma unroll
        for (int n = 0; n < 4; ++n) Cp[rb + n * 16] = f2b(acc[m][n][jj]);
      }
  } else if constexpr (MODE == 1) {
    unsigned short* Cp = (unsigned short*)C + (long long)bz * strideC;
    const float* rs = rowS + bz * scaleStride;
    const float* cs = colS + bz * scaleStride;
    float csv[4];
#pragma unroll
    for (int n = 0; n < 4; ++n) csv[n] = cs[c0 + n * 16];
#pragma unroll
    for (int m = 0; m < MF; ++m)
#pragma unroll
      for (int jj = 0; jj < 4; ++jj) {
        const int rr = rbase + m * 16 + jj;
        const float rsv = rs[rr];
        const long long rb = (long long)rr * ldc + c0;
#pragma unroll
        for (int n = 0; n < 4; ++n) Cp[rb + n * 16] = f2b(acc[m][n][jj] * rsv * csv[n]);
      }
  } else {
    float* Cp = (float*)C + (long long)bz * strideC;
#pragma unroll
    for (int m = 0; m < MF; ++m)
#pragma unroll
      for (int jj = 0; jj < 4; ++jj) {
        const long long rb = (long long)(rbase + m * 16 + jj) * ldc + c0;
#pragma unroll
        for (int n = 0; n < 4; ++n) Cp[rb + n * 16] = acc[m][n][jj];
      }
  }
}

// ---------------- launch ----------------

extern "C" void kernel_launch(void* const* d_in, const int* in_sizes, int n_in,
                              void* d_out, int out_size, void* d_ws, size_t ws_size,
                              hipStream_t stream) {
  (void)in_sizes; (void)n_in; (void)out_size; (void)ws_size;
  const float* x1 = (const float*)d_in[0];
  const float* x2 = (const float*)d_in[1];
  const float* WQ = (const float*)d_in[2];
  const float* WK = (const float*)d_in[3];
  const float* WV = (const float*)d_in[4];
  float* out = (float*)d_out;
  char* ws = (char*)d_ws;

  const long long MB16 = 16777216LL;
  unsigned short* qb = (unsigned short*)(ws);
  unsigned short* kb = (unsigned short*)(ws + MB16);
  unsigned short* vT = (unsigned short*)(ws + 2 * MB16);
  float* rq = (float*)(ws + 3 * MB16);
  float* rk = (float*)(ws + 3 * MB16 + 32768);
  char* scr = ws + 3 * MB16 + 65536;
  unsigned short* x1b = (unsigned short*)(scr);
  unsigned short* x2b = (unsigned short*)(scr + MB16);
  unsigned short* wqT = (unsigned short*)(scr + 2 * MB16);
  unsigned short* wkT = (unsigned short*)(scr + 2 * MB16 + 2097152);
  unsigned short* wvT = (unsigned short*)(scr + 2 * MB16 + 2 * 2097152);
  unsigned short* zb  = (unsigned short*)(scr);  // reused after projections

  cvt_f32_bf16<<<4096, 256, 0, stream>>>(x1, x1b);
  cvt_f32_bf16<<<4096, 256, 0, stream>>>(x2, x2b);
  cvt_w_T<<<dim3(32, 32, 3), 256, 0, stream>>>(WQ, WK, WV, wqT, wkT, wvT);

  // merged q+k projection: rows 0..8191 vs WQ, 8192..16383 vs WK; C = qb||kb
  gemmp<0, 0><<<dim3(4, 64, 1), 512, 0, stream>>>(
      x1b, wqT, wkT, 8192, qb, 1024, 1024, 1024, 1024, 0, 0, 0, nullptr, nullptr, 0);

  // vT[e, n] = sum_k WV[k,e] * x2[n,k] (v transposed), TALL 128x256: grid (32,8)=256
  gemmp<0, 1><<<dim3(32, 8, 1), 512, 0, stream>>>(
      wvT, x2b, x2b, 1 << 30, vT, 1024, 1024, 1024, 8192, 0, 0, 0, nullptr, nullptr, 0);

  rownorm<<<16384, 256, 0, stream>>>(qb, kb, rq, rk);

  // cosine scores z[b] = (q k^T) * rq x rk -> bf16, 256x256: grid (8,8,4)=256
  gemmp<1, 0><<<dim3(8, 8, 4), 512, 0, stream>>>(
      qb, kb, kb, 1 << 30, zb, 1024, 1024, 1024, 2048,
      2048LL * 1024, 2048LL * 1024, 2048LL * 2048, rq, rk, 2048);

  softmax_rows<<<8192, 256, 0, stream>>>(zb);

  // y[b] = w[b] @ v[b] via BT-gemm vs vT, TALL 128x256: grid (4,16,4)=256, fp32 out
  gemmp<2, 1><<<dim3(4, 16, 4), 512, 0, stream>>>(
      zb, vT, vT, 1 << 30, out, 2048, 2048, 8192, 1024,
      2048LL * 2048, 2048, 2048LL * 1024, nullptr, nullptr, 0);
}

// Round 6
// 285.605 us; speedup vs baseline: 1.1163x; 1.1163x over previous
//
#include <hip/hip_runtime.h>

// ContentBasedAttention: y = softmax(cos_sim(x1@WQ, x2@WK)) @ (x2@WV)
// B=4, S=2048, D=1024. fp32 in/out; internal bf16 MFMA.
// GEMM engine (round-4 gemmk schedule + occupancy fix): BK=32, 3 LDS buffers,
// 2-tile prefetch lookahead, counted vmcnt (steady 3/4, 0 only at tail),
// paired-row XOR-swizzled LDS (round-3-measured 0 conflicts), global_load_lds
// staging with pre-swizzled per-thread source (rule 21).
// Two tile shapes, every launch = 512 blocks:
//   SMALL=0: 256x128, 512 thr (8 waves 4Mx2N), 72KB LDS -> 2 blocks/CU
//   SMALL=1: 128x128, 256 thr (4 waves 2Mx2N), 48KB LDS -> 3 blocks/CU

typedef __attribute__((ext_vector_type(4))) float f32x4;
typedef __attribute__((ext_vector_type(4))) unsigned short u16x4;
typedef __attribute__((ext_vector_type(8))) unsigned short u16x8;
typedef __attribute__((ext_vector_type(8))) __bf16 bf16x8;

__device__ __forceinline__ unsigned short f2b(float f) {
  unsigned u = __float_as_uint(f);
  u += 0x7FFFu + ((u >> 16) & 1u);
  return (unsigned short)(u >> 16);
}
__device__ __forceinline__ float b2f(unsigned short h) {
  return __uint_as_float(((unsigned)h) << 16);
}

__device__ __forceinline__ void gl_lds16(const void* g, void* l) {
  __builtin_amdgcn_global_load_lds(
      (const __attribute__((address_space(1))) void*)g,
      (__attribute__((address_space(3))) void*)l, 16, 0, 0);
}

// ---------------- elementwise converts ----------------

__global__ void cvt_f32_bf16(const float* __restrict__ in, unsigned short* __restrict__ out) {
  long long i = (long long)(blockIdx.x * 256 + threadIdx.x) * 8;
  f32x4 a = *(const f32x4*)(in + i);
  f32x4 b = *(const f32x4*)(in + i + 4);
  u16x8 o;
  o[0] = f2b(a[0]); o[1] = f2b(a[1]); o[2] = f2b(a[2]); o[3] = f2b(a[3]);
  o[4] = f2b(b[0]); o[5] = f2b(b[1]); o[6] = f2b(b[2]); o[7] = f2b(b[3]);
  *(u16x8*)(out + i) = o;
}

__global__ void cvt_w_T(const float* __restrict__ w0, const float* __restrict__ w1,
                        const float* __restrict__ w2,
                        unsigned short* __restrict__ o0, unsigned short* __restrict__ o1,
                        unsigned short* __restrict__ o2) {
  const float* src = blockIdx.z == 0 ? w0 : (blockIdx.z == 1 ? w1 : w2);
  unsigned short* dst = blockIdx.z == 0 ? o0 : (blockIdx.z == 1 ? o1 : o2);
  __shared__ float tile[32][33];
  const int t = threadIdx.x;
  const int r = t >> 3, c4 = (t & 7) << 2;
  f32x4 v = *(const f32x4*)(src + (long long)(blockIdx.y * 32 + r) * 1024 + blockIdx.x * 32 + c4);
  tile[r][c4 + 0] = v[0]; tile[r][c4 + 1] = v[1];
  tile[r][c4 + 2] = v[2]; tile[r][c4 + 3] = v[3];
  __syncthreads();
  u16x4 ov;
  ov[0] = f2b(tile[c4 + 0][r]); ov[1] = f2b(tile[c4 + 1][r]);
  ov[2] = f2b(tile[c4 + 2][r]); ov[3] = f2b(tile[c4 + 3][r]);
  *(u16x4*)(dst + (long long)(blockIdx.x * 32 + r) * 1024 + blockIdx.y * 32 + c4) = ov;
}

// ---------------- per-row rsqrt(sum sq) ----------------

__global__ void rownorm(const unsigned short* __restrict__ qb, const unsigned short* __restrict__ kb,
                        float* __restrict__ rq, float* __restrict__ rk) {
  const int row = blockIdx.x;
  const unsigned short* src;
  float* dst;
  if (row < 8192) { src = qb + (long long)row * 1024; dst = rq + row; }
  else            { src = kb + (long long)(row - 8192) * 1024; dst = rk + (row - 8192); }
  const int t = threadIdx.x;
  u16x4 v = *(const u16x4*)(src + t * 4);
  float s = 0.f;
#pragma unroll
  for (int i = 0; i < 4; ++i) { float f = b2f(v[i]); s += f * f; }
#pragma unroll
  for (int o = 32; o; o >>= 1) s += __shfl_xor(s, o);
  __shared__ float red[4];
  if ((t & 63) == 0) red[t >> 6] = s;
  __syncthreads();
  if (t == 0) {
    float tot = red[0] + red[1] + red[2] + red[3];
    *dst = rsqrtf(fmaxf(tot, 1e-12f));
  }
}

// ---------------- in-place row softmax over bf16 [*, 2048] ----------------

__global__ void softmax_rows(unsigned short* __restrict__ zb) {
  unsigned short* zr = zb + (long long)blockIdx.x * 2048;
  const int t = threadIdx.x;
  u16x8 v = *(const u16x8*)(zr + t * 8);
  float f[8];
#pragma unroll
  for (int i = 0; i < 8; ++i) f[i] = b2f(v[i]);
  float mx = f[0];
#pragma unroll
  for (int i = 1; i < 8; ++i) mx = fmaxf(mx, f[i]);
#pragma unroll
  for (int o = 32; o; o >>= 1) mx = fmaxf(mx, __shfl_xor(mx, o));
  __shared__ float red[4];
  if ((t & 63) == 0) red[t >> 6] = mx;
  __syncthreads();
  mx = fmaxf(fmaxf(red[0], red[1]), fmaxf(red[2], red[3]));
  float s = 0.f;
#pragma unroll
  for (int i = 0; i < 8; ++i) { f[i] = __expf(f[i] - mx); s += f[i]; }
  __syncthreads();
#pragma unroll
  for (int o = 32; o; o >>= 1) s += __shfl_xor(s, o);
  if ((t & 63) == 0) red[t >> 6] = s;
  __syncthreads();
  s = red[0] + red[1] + red[2] + red[3];
  float inv = 1.0f / s;
  u16x8 o8;
#pragma unroll
  for (int i = 0; i < 8; ++i) o8[i] = f2b(f[i] * inv);
  *(u16x8*)(zr + t * 8) = o8;
}

// ---------------- GEMM_BT engine ----------------
// C[m,n] = sum_k A[m,k]*B[n,k], row-major bf16. BM x 128, BK=32.
// Wave tile 64x64 (16 MFMA / 8 ds_read_b128 per tile). LDS regions [rows][32]
// with paired-row swizzle: logical (row g=2R+a, colquad q) at slot (4a+q)^(R&7)
// -> fragment reads land 2 lanes/bank (free, m136); staged linearly via
// global_load_lds with the involution applied to the per-thread SOURCE address.
// Pipeline: 3 buffers; tile kt stages tile kt+2; tile-end wait = steady
// vmcnt(L) (L = loads/thread/tile: 3 or 4), vmcnt(0) only at the tail;
// one barrier per tile. Occupancy (not LDS size) provides the overlap.
// MODE 0: bf16 C. MODE 1: bf16 of acc*rowS[m]*colS[n]. MODE 2: fp32 C.

template <int MODE, int SMALL>
__global__ __launch_bounds__(SMALL ? 256 : 512, SMALL ? 3 : 4) void gemmw(
    const unsigned short* __restrict__ A,
    const unsigned short* __restrict__ B0_, const unsigned short* __restrict__ B1_, int bSplit,
    void* __restrict__ C, int K, int lda, int ldb, int ldc,
    long long strideA, long long strideB, long long strideC,
    const float* __restrict__ rowS, const float* __restrict__ colS, int scaleStride) {
  constexpr int BM = SMALL ? 128 : 256;
  constexpr int AE = BM * 32;
  constexpr int BE = 128 * 32;
  __shared__ __align__(128) unsigned short sA[3][AE];
  __shared__ __align__(128) unsigned short sB[3][BE];

  // bijective XCD swizzle (nwg = 512 or 256, %8 == 0)
  const int gx = gridDim.x, gy = gridDim.y;
  int flat = blockIdx.x + gx * (blockIdx.y + gy * blockIdx.z);
  const int cpx = (gx * gy * gridDim.z) >> 3;
  flat = (flat & 7) * cpx + (flat >> 3);
  const int bx = flat % gx;
  const int rem = flat / gx;
  const int by = rem % gy;
  const int bz = rem / gy;

  const int bm0 = by * BM, bn0 = bx << 7;
  const unsigned short* Ab = A + (long long)bz * strideA;
  const unsigned short* Bb = ((bm0 < bSplit) ? B0_ : B1_) + (long long)bz * strideB;

  const int t = threadIdx.x, l = t & 63, w = t >> 6;
  const int wr = w >> 1, wc = w & 1;   // 4Mx2N (SMALL: 2Mx2N), wave tile 64x64
  const int fr = l & 15, fq = l >> 4;
  const long long ldaL = lda, ldbL = ldb;

  // swizzled per-lane read offset (elems) within a [rows][32] region; fragment
  // base rows are multiples of 16 so (base/2)&7 == 0 and lofs is base-invariant
  const int R0 = fr >> 1;
  const int lofs = R0 * 64 + ((((fr & 1) << 2) | fq) ^ R0) * 8;

  // per-thread staging source (involution of the read swizzle)
  const int aq = (t & 7) ^ ((t >> 3) & 7);
  const int g0 = ((t >> 3) << 1) + (aq >> 2);
  const int q8 = (aq & 3) << 3;
  const unsigned short* gA_t = Ab + (long long)(bm0 + g0) * ldaL + q8;
  const unsigned short* gB_t = Bb + (long long)(bn0 + g0) * ldbL + q8;

  // stage one full K-tile into buffer nb (L = SMALL?4:3 loads/thread)
  auto STAGE = [&](int kc, int nb) {
    if constexpr (!SMALL) {
      gl_lds16(gA_t + kc, &sA[nb][t * 8]);
      gl_lds16(gA_t + (long long)128 * ldaL + kc, &sA[nb][t * 8 + 4096]);
      gl_lds16(gB_t + kc, &sB[nb][t * 8]);
    } else {
      gl_lds16(gA_t + kc, &sA[nb][t * 8]);
      gl_lds16(gA_t + (long long)64 * ldaL + kc, &sA[nb][t * 8 + 2048]);
      gl_lds16(gB_t + kc, &sB[nb][t * 8]);
      gl_lds16(gB_t + (long long)64 * ldbL + kc, &sB[nb][t * 8 + 2048]);
    }
  };

  f32x4 acc[4][4] = {};
  const int NKT = K >> 5;
  const int arow = wr * 64, bcol = wc * 64;

  // prologue: stage tiles 0,1; wait tile 0 landed (tile 1's L stay in flight)
  STAGE(0, 0);
  STAGE(32, 1);
  if constexpr (!SMALL) asm volatile("s_waitcnt vmcnt(3)" ::: "memory");
  else                  asm volatile("s_waitcnt vmcnt(4)" ::: "memory");
  __builtin_amdgcn_s_barrier();

  int cur = 0, nxt = 1, nn2 = 2;
  for (int kt = 0; kt < NKT; ++kt) {
    const unsigned short* aR = &sA[cur][0];
    const unsigned short* bR = &sB[cur][0];
    bf16x8 af[4], bfr[4];
#pragma unroll
    for (int m = 0; m < 4; ++m)
      af[m] = *(const bf16x8*)(aR + (arow + m * 16) * 32 + lofs);
#pragma unroll
    for (int n = 0; n < 4; ++n)
      bfr[n] = *(const bf16x8*)(bR + (bcol + n * 16) * 32 + lofs);

    if (kt + 2 < NKT) STAGE((kt + 2) << 5, nn2);

    __builtin_amdgcn_s_setprio(1);
#pragma unroll
    for (int m = 0; m < 4; ++m)
#pragma unroll
      for (int n = 0; n < 4; ++n)
        acc[m][n] = __builtin_amdgcn_mfma_f32_16x16x32_bf16(af[m], bfr[n], acc[m][n], 0, 0, 0);
    __builtin_amdgcn_s_setprio(0);

    // tile-end counted wait: buffer nxt must be landed before next iteration
    if (kt + 2 < NKT) {
      if constexpr (!SMALL) asm volatile("s_waitcnt vmcnt(3)" ::: "memory");
      else                  asm volatile("s_waitcnt vmcnt(4)" ::: "memory");
    } else if (kt + 1 < NKT) {
      asm volatile("s_waitcnt vmcnt(0)" ::: "memory");
    }
    __builtin_amdgcn_s_barrier();
    const int tmp = cur; cur = nxt; nxt = nn2; nn2 = tmp;
  }

  // epilogue: acc[m][n][jj] -> row bm0 + arow + m*16 + fq*4 + jj,
  //           col bn0 + bcol + n*16 + fr
  const int rbase = bm0 + arow + fq * 4;
  const int c0 = bn0 + bcol + fr;
  if constexpr (MODE == 0) {
    unsigned short* Cp = (unsigned short*)C + (long long)bz * strideC;
#pragma unroll
    for (int m = 0; m < 4; ++m)
#pragma unroll
      for (int jj = 0; jj < 4; ++jj) {
        const long long rb = (long long)(rbase + m * 16 + jj) * ldc + c0;
#pragma unroll
        for (int n = 0; n < 4; ++n) Cp[rb + n * 16] = f2b(acc[m][n][jj]);
      }
  } else if constexpr (MODE == 1) {
    unsigned short* Cp = (unsigned short*)C + (long long)bz * strideC;
    const float* rs = rowS + bz * scaleStride;
    const float* cs = colS + bz * scaleStride;
    float csv[4];
#pragma unroll
    for (int n = 0; n < 4; ++n) csv[n] = cs[c0 + n * 16];
#pragma unroll
    for (int m = 0; m < 4; ++m)
#pragma unroll
      for (int jj = 0; jj < 4; ++jj) {
        const int rr = rbase + m * 16 + jj;
        const float rsv = rs[rr];
        const long long rb = (long long)rr * ldc + c0;
#pragma unroll
        for (int n = 0; n < 4; ++n) Cp[rb + n * 16] = f2b(acc[m][n][jj] * rsv * csv[n]);
      }
  } else {
    float* Cp = (float*)C + (long long)bz * strideC;
#pragma unroll
    for (int m = 0; m < 4; ++m)
#pragma unroll
      for (int jj = 0; jj < 4; ++jj) {
        const long long rb = (long long)(rbase + m * 16 + jj) * ldc + c0;
#pragma unroll
        for (int n = 0; n < 4; ++n) Cp[rb + n * 16] = acc[m][n][jj];
      }
  }
}

// ---------------- launch ----------------

extern "C" void kernel_launch(void* const* d_in, const int* in_sizes, int n_in,
                              void* d_out, int out_size, void* d_ws, size_t ws_size,
                              hipStream_t stream) {
  (void)in_sizes; (void)n_in; (void)out_size; (void)ws_size;
  const float* x1 = (const float*)d_in[0];
  const float* x2 = (const float*)d_in[1];
  const float* WQ = (const float*)d_in[2];
  const float* WK = (const float*)d_in[3];
  const float* WV = (const float*)d_in[4];
  float* out = (float*)d_out;
  char* ws = (char*)d_ws;

  const long long MB16 = 16777216LL;
  unsigned short* qb = (unsigned short*)(ws);
  unsigned short* kb = (unsigned short*)(ws + MB16);
  unsigned short* vT = (unsigned short*)(ws + 2 * MB16);
  float* rq = (float*)(ws + 3 * MB16);
  float* rk = (float*)(ws + 3 * MB16 + 32768);
  char* scr = ws + 3 * MB16 + 65536;
  unsigned short* x1b = (unsigned short*)(scr);
  unsigned short* x2b = (unsigned short*)(scr + MB16);
  unsigned short* wqT = (unsigned short*)(scr + 2 * MB16);
  unsigned short* wkT = (unsigned short*)(scr + 2 * MB16 + 2097152);
  unsigned short* wvT = (unsigned short*)(scr + 2 * MB16 + 2 * 2097152);
  unsigned short* zb  = (unsigned short*)(scr);  // reused after projections

  cvt_f32_bf16<<<4096, 256, 0, stream>>>(x1, x1b);
  cvt_f32_bf16<<<4096, 256, 0, stream>>>(x2, x2b);
  cvt_w_T<<<dim3(32, 32, 3), 256, 0, stream>>>(WQ, WK, WV, wqT, wkT, wvT);

  // merged q+k projection: rows 0..8191 vs WQ, 8192..16383 vs WK; C = qb||kb
  // 256x128 tiles: grid (1024/128, 16384/256) = (8,64) = 512 blocks, 2/CU
  gemmw<0, 0><<<dim3(8, 64, 1), 512, 0, stream>>>(
      x1b, wqT, wkT, 8192, qb, 1024, 1024, 1024, 1024, 0, 0, 0, nullptr, nullptr, 0);

  // vT[e, n] = sum_k WV[k,e] * x2[n,k] (v transposed)
  // 128x128 tiles: grid (8192/128, 1024/128) = (64,8) = 512 blocks, 3/CU
  gemmw<0, 1><<<dim3(64, 8, 1), 256, 0, stream>>>(
      wvT, x2b, x2b, 1 << 30, vT, 1024, 1024, 1024, 8192, 0, 0, 0, nullptr, nullptr, 0);

  rownorm<<<16384, 256, 0, stream>>>(qb, kb, rq, rk);

  // cosine scores z[b] = (q k^T) * rq x rk -> bf16
  // 256x128 tiles: grid (2048/128, 2048/256, 4) = (16,8,4) = 512 blocks
  gemmw<1, 0><<<dim3(16, 8, 4), 512, 0, stream>>>(
      qb, kb, kb, 1 << 30, zb, 1024, 1024, 1024, 2048,
      2048LL * 1024, 2048LL * 1024, 2048LL * 2048, rq, rk, 2048);

  softmax_rows<<<8192, 256, 0, stream>>>(zb);

  // y[b] = w[b] @ v[b] via BT-gemm vs vT (batch b at cols b*2048)
  // 128x128 tiles: grid (1024/128, 2048/128, 4) = (8,16,4) = 512 blocks, fp32 out
  gemmw<2, 1><<<dim3(8, 16, 4), 256, 0, stream>>>(
      zb, vT, vT, 1 << 30, out, 2048, 2048, 8192, 1024,
      2048LL * 2048, 2048, 2048LL * 1024, nullptr, nullptr, 0);
}

// Round 7
// 280.830 us; speedup vs baseline: 1.1353x; 1.0170x over previous
//
#include <hip/hip_runtime.h>

// ContentBasedAttention: y = softmax(cos_sim(x1@WQ, x2@WK)) @ (x2@WV)
// B=4, S=2048, D=1024. fp32 in/out; internal bf16 MFMA.
// Two GEMM engines:
//  gemm2 (proj, scores): 256x256, BK=64, 8 waves, m201-style 4-phase/K-tile
//    schedule with spread half-tile staging + counted vmcnt(2) (never 0 mid-loop).
//  gemmw (vT, PV): round-4/6 proven 128x128 BK=32 3-buffer 2-lookahead engine.
// Both use the paired-row XOR-swizzled LDS (measured 0 bank conflicts) staged
// via global_load_lds with the swizzle involution applied to the SOURCE (rule 21).

typedef __attribute__((ext_vector_type(4))) float f32x4;
typedef __attribute__((ext_vector_type(4))) unsigned short u16x4;
typedef __attribute__((ext_vector_type(8))) unsigned short u16x8;
typedef __attribute__((ext_vector_type(8))) __bf16 bf16x8;

__device__ __forceinline__ unsigned short f2b(float f) {
  unsigned u = __float_as_uint(f);
  u += 0x7FFFu + ((u >> 16) & 1u);
  return (unsigned short)(u >> 16);
}
__device__ __forceinline__ float b2f(unsigned short h) {
  return __uint_as_float(((unsigned)h) << 16);
}

__device__ __forceinline__ void gl_lds16(const void* g, void* l) {
  __builtin_amdgcn_global_load_lds(
      (const __attribute__((address_space(1))) void*)g,
      (__attribute__((address_space(3))) void*)l, 16, 0, 0);
}

// ---------------- elementwise converts ----------------

__global__ void cvt_f32_bf16(const float* __restrict__ in, unsigned short* __restrict__ out) {
  long long i = (long long)(blockIdx.x * 256 + threadIdx.x) * 8;
  f32x4 a = *(const f32x4*)(in + i);
  f32x4 b = *(const f32x4*)(in + i + 4);
  u16x8 o;
  o[0] = f2b(a[0]); o[1] = f2b(a[1]); o[2] = f2b(a[2]); o[3] = f2b(a[3]);
  o[4] = f2b(b[0]); o[5] = f2b(b[1]); o[6] = f2b(b[2]); o[7] = f2b(b[3]);
  *(u16x8*)(out + i) = o;
}

__global__ void cvt_w_T(const float* __restrict__ w0, const float* __restrict__ w1,
                        const float* __restrict__ w2,
                        unsigned short* __restrict__ o0, unsigned short* __restrict__ o1,
                        unsigned short* __restrict__ o2) {
  const float* src = blockIdx.z == 0 ? w0 : (blockIdx.z == 1 ? w1 : w2);
  unsigned short* dst = blockIdx.z == 0 ? o0 : (blockIdx.z == 1 ? o1 : o2);
  __shared__ float tile[32][33];
  const int t = threadIdx.x;
  const int r = t >> 3, c4 = (t & 7) << 2;
  f32x4 v = *(const f32x4*)(src + (long long)(blockIdx.y * 32 + r) * 1024 + blockIdx.x * 32 + c4);
  tile[r][c4 + 0] = v[0]; tile[r][c4 + 1] = v[1];
  tile[r][c4 + 2] = v[2]; tile[r][c4 + 3] = v[3];
  __syncthreads();
  u16x4 ov;
  ov[0] = f2b(tile[c4 + 0][r]); ov[1] = f2b(tile[c4 + 1][r]);
  ov[2] = f2b(tile[c4 + 2][r]); ov[3] = f2b(tile[c4 + 3][r]);
  *(u16x4*)(dst + (long long)(blockIdx.x * 32 + r) * 1024 + blockIdx.y * 32 + c4) = ov;
}

// ---------------- per-row rsqrt(sum sq) ----------------

__global__ void rownorm(const unsigned short* __restrict__ qb, const unsigned short* __restrict__ kb,
                        float* __restrict__ rq, float* __restrict__ rk) {
  const int row = blockIdx.x;
  const unsigned short* src;
  float* dst;
  if (row < 8192) { src = qb + (long long)row * 1024; dst = rq + row; }
  else            { src = kb + (long long)(row - 8192) * 1024; dst = rk + (row - 8192); }
  const int t = threadIdx.x;
  u16x4 v = *(const u16x4*)(src + t * 4);
  float s = 0.f;
#pragma unroll
  for (int i = 0; i < 4; ++i) { float f = b2f(v[i]); s += f * f; }
#pragma unroll
  for (int o = 32; o; o >>= 1) s += __shfl_xor(s, o);
  __shared__ float red[4];
  if ((t & 63) == 0) red[t >> 6] = s;
  __syncthreads();
  if (t == 0) {
    float tot = red[0] + red[1] + red[2] + red[3];
    *dst = rsqrtf(fmaxf(tot, 1e-12f));
  }
}

// ---------------- in-place row softmax over bf16 [*, 2048] ----------------

__global__ void softmax_rows(unsigned short* __restrict__ zb) {
  unsigned short* zr = zb + (long long)blockIdx.x * 2048;
  const int t = threadIdx.x;
  u16x8 v = *(const u16x8*)(zr + t * 8);
  float f[8];
#pragma unroll
  for (int i = 0; i < 8; ++i) f[i] = b2f(v[i]);
  float mx = f[0];
#pragma unroll
  for (int i = 1; i < 8; ++i) mx = fmaxf(mx, f[i]);
#pragma unroll
  for (int o = 32; o; o >>= 1) mx = fmaxf(mx, __shfl_xor(mx, o));
  __shared__ float red[4];
  if ((t & 63) == 0) red[t >> 6] = mx;
  __syncthreads();
  mx = fmaxf(fmaxf(red[0], red[1]), fmaxf(red[2], red[3]));
  float s = 0.f;
#pragma unroll
  for (int i = 0; i < 8; ++i) { f[i] = __expf(f[i] - mx); s += f[i]; }
  __syncthreads();
#pragma unroll
  for (int o = 32; o; o >>= 1) s += __shfl_xor(s, o);
  if ((t & 63) == 0) red[t >> 6] = s;
  __syncthreads();
  s = red[0] + red[1] + red[2] + red[3];
  float inv = 1.0f / s;
  u16x8 o8;
#pragma unroll
  for (int i = 0; i < 8; ++i) o8[i] = f2b(f[i] * inv);
  *(u16x8*)(zr + t * 8) = o8;
}

// ---------------- gemm2: 256x256 BK=64 4-phase counted-vmcnt engine ----------------
// C[m,n] = sum_k A[m,k]*B[n,k], row-major bf16. 512 thr = 8 waves (2M x 4N),
// wave tile 128x64; per K-tile 4 phases, each = one C-quadrant (4m x 2n x 2ks
// = 16 MFMA) between raw barriers. Half-tiles (A0/A1/B0/B1 = 128 rows x 64 K,
// 2 gl_lds16/thread) staged 1-per-phase: kt's f0->B0(kt+1), f1->B1(kt+1),
// f2->A1(kt+1) [opposite buf, freed >=2 barriers earlier], f3->A0(kt+2)
// [current buf, its reads done at f2]. Single wait vmcnt(2)/K-tile at f3-end
// (covers kt+1's A0[5-phase lead],B0[4],B1[4],A1[1.3]); vmcnt(0) only at tail.
// LDS regions [256 rows][32] per (buf,ks), paired-row slot swizzle (0-conflict).

template <int MODE>
__global__ __launch_bounds__(512, 2) void gemm2(
    const unsigned short* __restrict__ A,
    const unsigned short* __restrict__ B0_, const unsigned short* __restrict__ B1_, int bSplit,
    void* __restrict__ C, int K, int lda, int ldb, int ldc,
    long long strideA, long long strideB, long long strideC,
    const float* __restrict__ rowS, const float* __restrict__ colS, int scaleStride) {
  __shared__ __align__(128) unsigned short sA[2][2][256 * 32];
  __shared__ __align__(128) unsigned short sB[2][2][256 * 32];

  // bijective XCD swizzle (nwg = 256, %8 == 0)
  const int gx = gridDim.x, gy = gridDim.y;
  int flat = blockIdx.x + gx * (blockIdx.y + gy * blockIdx.z);
  const int cpx = (gx * gy * gridDim.z) >> 3;
  flat = (flat & 7) * cpx + (flat >> 3);
  const int bx = flat % gx;
  const int rem = flat / gx;
  const int by = rem % gy;
  const int bz = rem / gy;

  const int bm0 = by << 8, bn0 = bx << 8;
  const unsigned short* Ab = A + (long long)bz * strideA;
  const unsigned short* Bb = ((bm0 < bSplit) ? B0_ : B1_) + (long long)bz * strideB;

  const int t = threadIdx.x, l = t & 63, w = t >> 6;
  const int wr = w >> 2, wc = w & 3;   // 2M x 4N, wave tile 128x64
  const int fr = l & 15, fq = l >> 4;
  const long long ldaL = lda, ldbL = ldb;

  // swizzled per-lane read offset within a [rows][32] region (base row %16 == 0)
  const int R0 = fr >> 1;
  const int lofs = R0 * 64 + ((((fr & 1) << 2) | fq) ^ R0) * 8;

  // per-thread staging source (involution of the read swizzle); 512 thr cover 128 rows
  const int aq = (t & 7) ^ ((t >> 3) & 7);
  const int g0 = ((t >> 3) << 1) + (aq >> 2);
  const int q8 = (aq & 3) << 3;
  const unsigned short* gA_t = Ab + (long long)(bm0 + g0) * ldaL + q8;
  const unsigned short* gB_t = Bb + (long long)(bn0 + g0) * ldbL + q8;

  // stage half-tile h of K-tile at kcol kc into buffer p:
  // h=0: A rows 0-127, h=1: A rows 128-255, h=2: B rows 0-127, h=3: B rows 128-255
  auto SP = [&](int kc, int p, int h) {
    if (h < 2) {
      gl_lds16(gA_t + (long long)(h * 128) * ldaL + kc,      &sA[p][0][h * 4096 + t * 8]);
      gl_lds16(gA_t + (long long)(h * 128) * ldaL + kc + 32, &sA[p][1][h * 4096 + t * 8]);
    } else {
      gl_lds16(gB_t + (long long)((h - 2) * 128) * ldbL + kc,      &sB[p][0][(h - 2) * 4096 + t * 8]);
      gl_lds16(gB_t + (long long)((h - 2) * 128) * ldbL + kc + 32, &sB[p][1][(h - 2) * 4096 + t * 8]);
    }
  };

  f32x4 acc[8][4] = {};
  const int NKT = K >> 6;
  const int wrow = wr * 128, bcol = wc * 64;

  // prologue: kt0 fully (A0,B0,B1,A1) + kt1.A0; wait kt0 landed (vmcnt(2))
  SP(0, 0, 0); SP(0, 0, 2); SP(0, 0, 3); SP(0, 0, 1);
  SP(64, 1, 0);
  asm volatile("s_waitcnt vmcnt(2)" ::: "memory");
  __builtin_amdgcn_s_barrier();

  for (int kt = 0; kt < NKT; ++kt) {
    const int p = kt & 1;
    const int kcn = (kt + 1) << 6;
    const bool s1 = (kt + 1 < NKT);
    const unsigned short* A0p = &sA[p][0][0];
    const unsigned short* A1p = &sA[p][1][0];
    const unsigned short* Bp0 = &sB[p][0][0];
    const unsigned short* Bp1 = &sB[p][1][0];
    bf16x8 af[4][2], bf0[2][2], bf1[2][2];

    // ---- f0: quadrant (mh0, nh0); stage kt+1.B0
#pragma unroll
    for (int m = 0; m < 4; ++m) {
      af[m][0] = *(const bf16x8*)(A0p + (wrow + m * 16) * 32 + lofs);
      af[m][1] = *(const bf16x8*)(A1p + (wrow + m * 16) * 32 + lofs);
    }
#pragma unroll
    for (int n = 0; n < 2; ++n) {
      bf0[n][0] = *(const bf16x8*)(Bp0 + (bcol + n * 16) * 32 + lofs);
      bf0[n][1] = *(const bf16x8*)(Bp1 + (bcol + n * 16) * 32 + lofs);
    }
    if (s1) SP(kcn, p ^ 1, 2);
    __builtin_amdgcn_s_barrier();
    asm volatile("s_waitcnt lgkmcnt(0)" ::: "memory");
    __builtin_amdgcn_s_setprio(1);
#pragma unroll
    for (int m = 0; m < 4; ++m)
#pragma unroll
      for (int n = 0; n < 2; ++n)
#pragma unroll
        for (int ks = 0; ks < 2; ++ks)
          acc[m][n] = __builtin_amdgcn_mfma_f32_16x16x32_bf16(af[m][ks], bf0[n][ks], acc[m][n], 0, 0, 0);
    __builtin_amdgcn_s_setprio(0);
    __builtin_amdgcn_s_barrier();

    // ---- f1: quadrant (mh0, nh1); stage kt+1.B1
#pragma unroll
    for (int n = 0; n < 2; ++n) {
      bf1[n][0] = *(const bf16x8*)(Bp0 + (bcol + 32 + n * 16) * 32 + lofs);
      bf1[n][1] = *(const bf16x8*)(Bp1 + (bcol + 32 + n * 16) * 32 + lofs);
    }
    if (s1) SP(kcn, p ^ 1, 3);
    __builtin_amdgcn_s_barrier();
    asm volatile("s_waitcnt lgkmcnt(0)" ::: "memory");
    __builtin_amdgcn_s_setprio(1);
#pragma unroll
    for (int m = 0; m < 4; ++m)
#pragma unroll
      for (int n = 0; n < 2; ++n)
#pragma unroll
        for (int ks = 0; ks < 2; ++ks)
          acc[m][2 + n] = __builtin_amdgcn_mfma_f32_16x16x32_bf16(af[m][ks], bf1[n][ks], acc[m][2 + n], 0, 0, 0);
    __builtin_amdgcn_s_setprio(0);
    __builtin_amdgcn_s_barrier();

    // ---- f2: quadrant (mh1, nh1); stage kt+1.A1
#pragma unroll
    for (int m = 0; m < 4; ++m) {
      af[m][0] = *(const bf16x8*)(A0p + (wrow + 64 + m * 16) * 32 + lofs);
      af[m][1] = *(const bf16x8*)(A1p + (wrow + 64 + m * 16) * 32 + lofs);
    }
    if (s1) SP(kcn, p ^ 1, 1);
    __builtin_amdgcn_s_barrier();
    asm volatile("s_waitcnt lgkmcnt(0)" ::: "memory");
    __builtin_amdgcn_s_setprio(1);
#pragma unroll
    for (int m = 0; m < 4; ++m)
#pragma unroll
      for (int n = 0; n < 2; ++n)
#pragma unroll
        for (int ks = 0; ks < 2; ++ks)
          acc[4 + m][2 + n] = __builtin_amdgcn_mfma_f32_16x16x32_bf16(af[m][ks], bf1[n][ks], acc[4 + m][2 + n], 0, 0, 0);
    __builtin_amdgcn_s_setprio(0);
    __builtin_amdgcn_s_barrier();

    // ---- f3: quadrant (mh1, nh0) — no LDS reads; stage kt+2.A0 (current buf)
    if (kt + 2 < NKT) SP((kt + 2) << 6, p, 0);
    __builtin_amdgcn_s_setprio(1);
#pragma unroll
    for (int m = 0; m < 4; ++m)
#pragma unroll
      for (int n = 0; n < 2; ++n)
#pragma unroll
        for (int ks = 0; ks < 2; ++ks)
          acc[4 + m][n] = __builtin_amdgcn_mfma_f32_16x16x32_bf16(af[m][ks], bf0[n][ks], acc[4 + m][n], 0, 0, 0);
    __builtin_amdgcn_s_setprio(0);
    if (kt + 2 < NKT)      asm volatile("s_waitcnt vmcnt(2)" ::: "memory");
    else if (kt + 1 < NKT) asm volatile("s_waitcnt vmcnt(0)" ::: "memory");
    __builtin_amdgcn_s_barrier();
  }

  // epilogue: acc[mi][nj][jj] -> row bm0+wrow+(mi>>2)*64+(mi&3)*16+fq*4+jj,
  //           col bn0+bcol+(nj>>1)*32+(nj&1)*16+fr
  const int rbase = bm0 + wrow + fq * 4;
  const int c0 = bn0 + bcol + fr;
  if constexpr (MODE == 0) {
    unsigned short* Cp = (unsigned short*)C + (long long)bz * strideC;
#pragma unroll
    for (int mi = 0; mi < 8; ++mi)
#pragma unroll
      for (int jj = 0; jj < 4; ++jj) {
        const int rr = rbase + (mi >> 2) * 64 + (mi & 3) * 16 + jj;
        const long long rb = (long long)rr * ldc + c0;
#pragma unroll
        for (int nj = 0; nj < 4; ++nj)
          Cp[rb + (nj >> 1) * 32 + (nj & 1) * 16] = f2b(acc[mi][nj][jj]);
      }
  } else {
    unsigned short* Cp = (unsigned short*)C + (long long)bz * strideC;
    const float* rs = rowS + bz * scaleStride;
    const float* cs = colS + bz * scaleStride;
    float csv[4];
#pragma unroll
    for (int nj = 0; nj < 4; ++nj) csv[nj] = cs[c0 + (nj >> 1) * 32 + (nj & 1) * 16];
#pragma unroll
    for (int mi = 0; mi < 8; ++mi)
#pragma unroll
      for (int jj = 0; jj < 4; ++jj) {
        const int rr = rbase + (mi >> 2) * 64 + (mi & 3) * 16 + jj;
        const float rsv = rs[rr];
        const long long rb = (long long)rr * ldc + c0;
#pragma unroll
        for (int nj = 0; nj < 4; ++nj)
          Cp[rb + (nj >> 1) * 32 + (nj & 1) * 16] = f2b(acc[mi][nj][jj] * rsv * csv[nj]);
      }
  }
}

// ---------------- gemmw: 128x128 BK=32 3-buffer engine (round-6, unchanged) ----------------
// MODE 0: bf16 C. MODE 2: fp32 C.

template <int MODE>
__global__ __launch_bounds__(256, 3) void gemmw(
    const unsigned short* __restrict__ A,
    const unsigned short* __restrict__ B0_, const unsigned short* __restrict__ B1_, int bSplit,
    void* __restrict__ C, int K, int lda, int ldb, int ldc,
    long long strideA, long long strideB, long long strideC) {
  __shared__ __align__(128) unsigned short sA[3][128 * 32];
  __shared__ __align__(128) unsigned short sB[3][128 * 32];

  const int gx = gridDim.x, gy = gridDim.y;
  int flat = blockIdx.x + gx * (blockIdx.y + gy * blockIdx.z);
  const int cpx = (gx * gy * gridDim.z) >> 3;
  flat = (flat & 7) * cpx + (flat >> 3);
  const int bx = flat % gx;
  const int rem = flat / gx;
  const int by = rem % gy;
  const int bz = rem / gy;

  const int bm0 = by << 7, bn0 = bx << 7;
  const unsigned short* Ab = A + (long long)bz * strideA;
  const unsigned short* Bb = ((bm0 < bSplit) ? B0_ : B1_) + (long long)bz * strideB;

  const int t = threadIdx.x, l = t & 63, w = t >> 6;
  const int wr = w >> 1, wc = w & 1;
  const int fr = l & 15, fq = l >> 4;
  const long long ldaL = lda, ldbL = ldb;

  const int R0 = fr >> 1;
  const int lofs = R0 * 64 + ((((fr & 1) << 2) | fq) ^ R0) * 8;

  const int aq = (t & 7) ^ ((t >> 3) & 7);
  const int g0 = ((t >> 3) << 1) + (aq >> 2);
  const int q8 = (aq & 3) << 3;
  const unsigned short* gA_t = Ab + (long long)(bm0 + g0) * ldaL + q8;
  const unsigned short* gB_t = Bb + (long long)(bn0 + g0) * ldbL + q8;

  auto STAGE = [&](int kc, int nb) {
    gl_lds16(gA_t + kc, &sA[nb][t * 8]);
    gl_lds16(gA_t + (long long)64 * ldaL + kc, &sA[nb][t * 8 + 2048]);
    gl_lds16(gB_t + kc, &sB[nb][t * 8]);
    gl_lds16(gB_t + (long long)64 * ldbL + kc, &sB[nb][t * 8 + 2048]);
  };

  f32x4 acc[4][4] = {};
  const int NKT = K >> 5;
  const int arow = wr * 64, bcol = wc * 64;

  STAGE(0, 0);
  STAGE(32, 1);
  asm volatile("s_waitcnt vmcnt(4)" ::: "memory");
  __builtin_amdgcn_s_barrier();

  int cur = 0, nxt = 1, nn2 = 2;
  for (int kt = 0; kt < NKT; ++kt) {
    const unsigned short* aR = &sA[cur][0];
    const unsigned short* bR = &sB[cur][0];
    bf16x8 af[4], bfr[4];
#pragma unroll
    for (int m = 0; m < 4; ++m)
      af[m] = *(const bf16x8*)(aR + (arow + m * 16) * 32 + lofs);
#pragma unroll
    for (int n = 0; n < 4; ++n)
      bfr[n] = *(const bf16x8*)(bR + (bcol + n * 16) * 32 + lofs);

    if (kt + 2 < NKT) STAGE((kt + 2) << 5, nn2);

    __builtin_amdgcn_s_setprio(1);
#pragma unroll
    for (int m = 0; m < 4; ++m)
#pragma unroll
      for (int n = 0; n < 4; ++n)
        acc[m][n] = __builtin_amdgcn_mfma_f32_16x16x32_bf16(af[m], bfr[n], acc[m][n], 0, 0, 0);
    __builtin_amdgcn_s_setprio(0);

    if (kt + 2 < NKT) {
      asm volatile("s_waitcnt vmcnt(4)" ::: "memory");
    } else if (kt + 1 < NKT) {
      asm volatile("s_waitcnt vmcnt(0)" ::: "memory");
    }
    __builtin_amdgcn_s_barrier();
    const int tmp = cur; cur = nxt; nxt = nn2; nn2 = tmp;
  }

  const int rbase = bm0 + arow + fq * 4;
  const int c0 = bn0 + bcol + fr;
  if constexpr (MODE == 0) {
    unsigned short* Cp = (unsigned short*)C + (long long)bz * strideC;
#pragma unroll
    for (int m = 0; m < 4; ++m)
#pragma unroll
      for (int jj = 0; jj < 4; ++jj) {
        const long long rb = (long long)(rbase + m * 16 + jj) * ldc + c0;
#pragma unroll
        for (int n = 0; n < 4; ++n) Cp[rb + n * 16] = f2b(acc[m][n][jj]);
      }
  } else {
    float* Cp = (float*)C + (long long)bz * strideC;
#pragma unroll
    for (int m = 0; m < 4; ++m)
#pragma unroll
      for (int jj = 0; jj < 4; ++jj) {
        const long long rb = (long long)(rbase + m * 16 + jj) * ldc + c0;
#pragma unroll
        for (int n = 0; n < 4; ++n) Cp[rb + n * 16] = acc[m][n][jj];
      }
  }
}

// ---------------- launch ----------------

extern "C" void kernel_launch(void* const* d_in, const int* in_sizes, int n_in,
                              void* d_out, int out_size, void* d_ws, size_t ws_size,
                              hipStream_t stream) {
  (void)in_sizes; (void)n_in; (void)out_size; (void)ws_size;
  const float* x1 = (const float*)d_in[0];
  const float* x2 = (const float*)d_in[1];
  const float* WQ = (const float*)d_in[2];
  const float* WK = (const float*)d_in[3];
  const float* WV = (const float*)d_in[4];
  float* out = (float*)d_out;
  char* ws = (char*)d_ws;

  const long long MB16 = 16777216LL;
  unsigned short* qb = (unsigned short*)(ws);
  unsigned short* kb = (unsigned short*)(ws + MB16);
  unsigned short* vT = (unsigned short*)(ws + 2 * MB16);
  float* rq = (float*)(ws + 3 * MB16);
  float* rk = (float*)(ws + 3 * MB16 + 32768);
  char* scr = ws + 3 * MB16 + 65536;
  unsigned short* x1b = (unsigned short*)(scr);
  unsigned short* x2b = (unsigned short*)(scr + MB16);
  unsigned short* wqT = (unsigned short*)(scr + 2 * MB16);
  unsigned short* wkT = (unsigned short*)(scr + 2 * MB16 + 2097152);
  unsigned short* wvT = (unsigned short*)(scr + 2 * MB16 + 2 * 2097152);
  unsigned short* zb  = (unsigned short*)(scr);  // reused after projections

  cvt_f32_bf16<<<4096, 256, 0, stream>>>(x1, x1b);
  cvt_f32_bf16<<<4096, 256, 0, stream>>>(x2, x2b);
  cvt_w_T<<<dim3(32, 32, 3), 256, 0, stream>>>(WQ, WK, WV, wqT, wkT, wvT);

  // merged q+k projection: rows 0..8191 vs WQ, 8192..16383 vs WK; C = qb||kb
  // 256x256 tiles: grid (1024/256, 16384/256) = (4,64) = 256 blocks
  gemm2<0><<<dim3(4, 64, 1), 512, 0, stream>>>(
      x1b, wqT, wkT, 8192, qb, 1024, 1024, 1024, 1024, 0, 0, 0, nullptr, nullptr, 0);

  // vT[e, n] = sum_k WV[k,e] * x2[n,k] (v transposed)
  // 128x128 tiles: grid (64,8) = 512 blocks
  gemmw<0><<<dim3(64, 8, 1), 256, 0, stream>>>(
      wvT, x2b, x2b, 1 << 30, vT, 1024, 1024, 1024, 8192, 0, 0, 0);

  rownorm<<<16384, 256, 0, stream>>>(qb, kb, rq, rk);

  // cosine scores z[b] = (q k^T) * rq x rk -> bf16
  // 256x256 tiles: grid (8,8,4) = 256 blocks
  gemm2<1><<<dim3(8, 8, 4), 512, 0, stream>>>(
      qb, kb, kb, 1 << 30, zb, 1024, 1024, 1024, 2048,
      2048LL * 1024, 2048LL * 1024, 2048LL * 2048, rq, rk, 2048);

  softmax_rows<<<8192, 256, 0, stream>>>(zb);

  // y[b] = w[b] @ v[b] via BT-gemm vs vT (batch b at cols b*2048)
  // 128x128 tiles: grid (8,16,4) = 512 blocks, fp32 out
  gemmw<2><<<dim3(8, 16, 4), 256, 0, stream>>>(
      zb, vT, vT, 1 << 30, out, 2048, 2048, 8192, 1024,
      2048LL * 2048, 2048, 2048LL * 1024);
}